// Round 1
// baseline (725.465 us; speedup 1.0000x reference)
//
#include <hip/hip_runtime.h>
#include <math.h>

// Problem constants
#define CHUNKS 256   // B * (H/CS) * (W/CS) = 4*8*8
#define CCH    96    // C
#define DNC    192   // 2*C
#define LC     64    // CS*CS
#define NST    16    // state dim N
#define DTR    6     // dt rank
#define NPROJ  38    // DTR + 2*N

__device__ __forceinline__ float siluf_(float x) {
    return x / (1.f + __expf(-x));
}

// Direction permutation: xs[k][d][l] = x0[d][sperm(k,l)]; output of scan step l
// for direction k lands at spatial position sperm(k,l) (all involutions).
__device__ __forceinline__ int sperm(int k, int l) {
    int t = (k & 1) ? (((l & 7) << 3) | (l >> 3)) : l;
    return (k & 2) ? (63 - t) : t;
}

// K1: per-(b,c) spatial norm over 64x64, + SiLU, write chunked channel-last h.
__global__ void k1_spatialnorm(const float* __restrict__ x,
                               const float* __restrict__ gamma,
                               const float* __restrict__ beta,
                               float* __restrict__ h_store) {
    int bc = blockIdx.x;             // 0..383  (b*96 + c)
    int b = bc / CCH, c = bc % CCH;
    const float* xp = x + (size_t)bc * 4096;
    float s = 0.f, sq = 0.f;
    for (int i = threadIdx.x; i < 4096; i += 256) {
        float v = xp[i]; s += v; sq += v * v;
    }
    __shared__ float rs[256], rq[256];
    rs[threadIdx.x] = s; rq[threadIdx.x] = sq;
    __syncthreads();
    for (int off = 128; off > 0; off >>= 1) {
        if (threadIdx.x < off) {
            rs[threadIdx.x] += rs[threadIdx.x + off];
            rq[threadIdx.x] += rq[threadIdx.x + off];
        }
        __syncthreads();
    }
    float mean = rs[0] * (1.f / 4096.f);
    float var  = rq[0] * (1.f / 4096.f) - mean * mean;
    float rinv = rsqrtf(var + 1e-5f);
    float g = gamma[c], be = beta[c];
    for (int i = threadIdx.x; i < 4096; i += 256) {
        int hh = i >> 6, ww = i & 63;
        float v = (xp[i] - mean) * rinv * g + be;
        float a = siluf_(v);
        int chunk = b * 64 + (hh >> 3) * 8 + (ww >> 3);
        int pos   = (hh & 7) * 8 + (ww & 7);
        h_store[(size_t)chunk * (LC * CCH) + pos * CCH + c] = a;
    }
}

// K2: per-position LN over 96 channels + in_proj (96 -> 384).
// First 192 outputs -> conv input, d-major [chunk][d][pos]; last 192 -> z, pos-major.
__global__ void k2_ln_inproj(const float* __restrict__ h_store,
                             const float* __restrict__ ln1_g,
                             const float* __restrict__ ln1_b,
                             const float* __restrict__ Win,  // (96, 384)
                             float* __restrict__ xc_pre,
                             float* __restrict__ zbuf) {
    int chunk = blockIdx.x;
    __shared__ float xln[64][96];
    const float* hp = h_store + (size_t)chunk * (LC * CCH);
    if (threadIdx.x < 64) {
        int p = threadIdx.x;
        const float* row = hp + p * CCH;
        float m = 0.f;
        for (int c = 0; c < 96; c++) m += row[c];
        m *= (1.f / 96.f);
        float v = 0.f;
        for (int c = 0; c < 96; c++) { float d = row[c] - m; v += d * d; }
        v *= (1.f / 96.f);
        float rinv = rsqrtf(v + 1e-5f);
        for (int c = 0; c < 96; c++)
            xln[p][c] = (row[c] - m) * rinv * ln1_g[c] + ln1_b[c];
    }
    __syncthreads();
    for (int idx = threadIdx.x; idx < 64 * 384; idx += 256) {
        int p = idx / 384, j = idx - p * 384;
        const float* w = Win + j;
        float acc = 0.f;
        #pragma unroll 8
        for (int c = 0; c < 96; c++) acc += xln[p][c] * w[c * 384];
        if (j < 192) xc_pre[(size_t)chunk * 12288 + j * 64 + p] = acc;
        else         zbuf[(size_t)chunk * 12288 + p * 192 + (j - 192)] = acc;
    }
}

// K3: depthwise 3x3 conv (zero pad) + bias + SiLU -> x0[chunk][d][l]
__global__ void k3_dwconv(const float* __restrict__ xc_pre,
                          const float* __restrict__ conv_w,  // (192,1,3,3)
                          const float* __restrict__ conv_b,
                          float* __restrict__ x0g) {
    int bx = blockIdx.x;               // 0 .. 256*48-1
    int chunk = bx / 48;
    int d = (bx % 48) * 4 + (threadIdx.x >> 6);
    int p = threadIdx.x & 63;
    int r = p >> 3, cc = p & 7;
    const float* in = xc_pre + (size_t)chunk * 12288 + d * 64;
    const float* wk = conv_w + d * 9;
    float acc = conv_b[d];
    #pragma unroll
    for (int dh = 0; dh < 3; dh++) {
        int rr = r + dh - 1;
        if (rr < 0 || rr > 7) continue;
        #pragma unroll
        for (int dw = 0; dw < 3; dw++) {
            int cw = cc + dw - 1;
            if (cw < 0 || cw > 7) continue;
            acc += in[rr * 8 + cw] * wk[dh * 3 + dw];
        }
    }
    x0g[(size_t)chunk * 12288 + d * 64 + p] = siluf_(acc);
}

// K4: per-chunk: 4 directions x { x_proj (192->38), dt proj + softplus,
// 64-step selective scan with N=16 states per d-channel }, merged in LDS.
__global__ __launch_bounds__(192) void k4_scan(
        const float* __restrict__ x0g,
        const float* __restrict__ xpw,     // (K,38,192)
        const float* __restrict__ dtw,     // (K,192,6)
        const float* __restrict__ dtb,     // (K,192)
        const float* __restrict__ A_logs,  // (K*192,16)
        const float* __restrict__ Ds,      // (K*192)
        float* __restrict__ y_g) {
    int chunk = blockIdx.x;
    __shared__ float x0s[192][65];   // padded: scan reads column sl across d
    __shared__ float yac[192][65];
    __shared__ float dtsB[64][DTR];
    __shared__ float BsL[64][16];
    __shared__ float CsL[64][16];

    const float* xg = x0g + (size_t)chunk * 12288;
    for (int i = threadIdx.x; i < 12288; i += 192) {
        int d = i >> 6, l = i & 63;
        x0s[d][l] = xg[i];
        yac[d][l] = 0.f;
    }
    __syncthreads();

    int d = threadIdx.x;   // 0..191, this thread's channel
    for (int k = 0; k < 4; k++) {
        // x_dbl projection: 38 outputs per scan position
        for (int idx = threadIdx.x; idx < 64 * NPROJ; idx += 192) {
            int l = idx & 63, c = idx >> 6;
            int sl = sperm(k, l);
            const float* w = xpw + ((k * NPROJ + c) * 192);
            float acc = 0.f;
            #pragma unroll 8
            for (int dd = 0; dd < 192; dd++) acc += x0s[dd][sl] * w[dd];
            if (c < DTR)            dtsB[l][c] = acc;
            else if (c < DTR + 16)  BsL[l][c - DTR] = acc;
            else                    CsL[l][c - DTR - 16] = acc;
        }
        __syncthreads();

        // scan over 64 steps; thread owns channel d
        int gd = k * 192 + d;
        float a[16], hst[16];
        #pragma unroll
        for (int n = 0; n < 16; n++) {
            a[n] = -__expf(A_logs[gd * 16 + n]);
            hst[n] = 0.f;
        }
        float w6[6];
        #pragma unroll
        for (int r = 0; r < 6; r++) w6[r] = dtw[gd * 6 + r];
        float bias = dtb[gd], Dd = Ds[gd];
        for (int l = 0; l < 64; l++) {
            int sl = sperm(k, l);
            float u = x0s[d][sl];
            float dp = bias;
            #pragma unroll
            for (int r = 0; r < 6; r++) dp += dtsB[l][r] * w6[r];
            float delta = (dp > 20.f) ? dp : log1pf(__expf(dp));
            float du = delta * u;
            float y = 0.f;
            #pragma unroll
            for (int n = 0; n < 16; n++) {
                hst[n] = hst[n] * __expf(delta * a[n]) + du * BsL[l][n];
                y += hst[n] * CsL[l][n];
            }
            yac[d][sl] += y + Dd * u;
        }
        __syncthreads();
    }

    // write transposed: y_g[chunk][l][d]
    float* yo = y_g + (size_t)chunk * 12288;
    for (int i = threadIdx.x; i < 12288; i += 192) {
        int l = i / 192, dd = i - l * 192;
        yo[i] = yac[dd][l];
    }
}

// K5: outnorm LN(192) * silu(z) -> out_proj (192->96) + h residual, un-chunk,
// final out = x + alpha * xv
__global__ void k5_out(const float* __restrict__ y_g,
                       const float* __restrict__ zbuf,
                       const float* __restrict__ og,
                       const float* __restrict__ ob,
                       const float* __restrict__ Wout,   // (192,96)
                       const float* __restrict__ h_store,
                       const float* __restrict__ x,
                       const float* __restrict__ alpha,
                       float* __restrict__ out) {
    int chunk = blockIdx.x;
    __shared__ float g[64][192];
    const float* yp = y_g + (size_t)chunk * 12288;
    const float* zp = zbuf + (size_t)chunk * 12288;
    if (threadIdx.x < 64) {
        int p = threadIdx.x;
        const float* row = yp + p * 192;
        float m = 0.f;
        for (int i = 0; i < 192; i++) m += row[i];
        m *= (1.f / 192.f);
        float v = 0.f;
        for (int i = 0; i < 192; i++) { float dd = row[i] - m; v += dd * dd; }
        v *= (1.f / 192.f);
        float rinv = rsqrtf(v + 1e-5f);
        const float* zrow = zp + p * 192;
        for (int i = 0; i < 192; i++) {
            float ln = (row[i] - m) * rinv * og[i] + ob[i];
            float zv = zrow[i];
            g[p][i] = ln * siluf_(zv);
        }
    }
    __syncthreads();
    float al = alpha[0];
    int b = chunk >> 6, ch = chunk & 63;
    int chh = ch >> 3, chw = ch & 7;
    const float* hp = h_store + (size_t)chunk * (LC * CCH);
    for (int idx = threadIdx.x; idx < 64 * 96; idx += 256) {
        int p = idx / 96, c = idx - p * 96;
        float acc = 0.f;
        #pragma unroll 8
        for (int i = 0; i < 192; i++) acc += g[p][i] * Wout[i * 96 + c];
        float hnew = hp[p * 96 + c] + acc;
        int hh = chh * 8 + (p >> 3), ww = chw * 8 + (p & 7);
        size_t gi = (((size_t)b * 96 + c) * 64 + hh) * 64 + ww;
        out[gi] = x[gi] + al * hnew;
    }
}

extern "C" void kernel_launch(void* const* d_in, const int* in_sizes, int n_in,
                              void* d_out, int out_size, void* d_ws, size_t ws_size,
                              hipStream_t stream) {
    const float* x        = (const float*)d_in[0];
    const float* gamma    = (const float*)d_in[1];
    const float* beta     = (const float*)d_in[2];
    const float* alpha    = (const float*)d_in[3];
    const float* ln1_g    = (const float*)d_in[4];
    const float* ln1_b    = (const float*)d_in[5];
    const float* in_proj  = (const float*)d_in[6];
    const float* conv_w   = (const float*)d_in[7];
    const float* conv_b   = (const float*)d_in[8];
    const float* x_proj   = (const float*)d_in[9];
    const float* dt_w     = (const float*)d_in[10];
    const float* dt_b     = (const float*)d_in[11];
    const float* A_logs   = (const float*)d_in[12];
    const float* Ds       = (const float*)d_in[13];
    const float* onorm_g  = (const float*)d_in[14];
    const float* onorm_b  = (const float*)d_in[15];
    const float* out_proj = (const float*)d_in[16];
    float* out = (float*)d_out;

    float* ws      = (float*)d_ws;
    float* h_store = ws;                      // 256*64*96  = 1,572,864 f
    float* xc_pre  = ws + 1572864;            // 256*192*64 = 3,145,728 f
    float* zbuf    = xc_pre + 3145728;        // 3,145,728 f
    float* x0g     = zbuf + 3145728;          // 3,145,728 f
    float* y_gb    = xc_pre;                  // alias: xc_pre dead after k3

    hipLaunchKernelGGL(k1_spatialnorm, dim3(384), dim3(256), 0, stream,
                       x, gamma, beta, h_store);
    hipLaunchKernelGGL(k2_ln_inproj, dim3(256), dim3(256), 0, stream,
                       h_store, ln1_g, ln1_b, in_proj, xc_pre, zbuf);
    hipLaunchKernelGGL(k3_dwconv, dim3(256 * 48), dim3(256), 0, stream,
                       xc_pre, conv_w, conv_b, x0g);
    hipLaunchKernelGGL(k4_scan, dim3(256), dim3(192), 0, stream,
                       x0g, x_proj, dt_w, dt_b, A_logs, Ds, y_gb);
    hipLaunchKernelGGL(k5_out, dim3(256), dim3(256), 0, stream,
                       y_gb, zbuf, onorm_g, onorm_b, out_proj, h_store, x, alpha, out);
}

// Round 2
// 301.027 us; speedup vs baseline: 2.4100x; 2.4100x over previous
//
#include <hip/hip_runtime.h>
#include <math.h>

// Problem constants
#define NCHUNK 256   // B * (H/CS) * (W/CS) = 4*8*8
#define CCH    96    // C
#define DNC    192   // 2*C
#define LC     64    // CS*CS
#define NST    16    // state dim N
#define DTR    6     // dt rank

__device__ __forceinline__ float siluf_(float x) {
    return x / (1.f + __expf(-x));
}

// Direction permutation: xs[k][d][l] = x0[d][sperm(k,l)]; output of scan step l
// for direction k lands at spatial position sperm(k,l) (all involutions).
__device__ __forceinline__ int sperm(int k, int l) {
    int t = (k & 1) ? (((l & 7) << 3) | (l >> 3)) : l;
    return (k & 2) ? (63 - t) : t;
}

// ---------------------------------------------------------------- k1a: stats
__global__ void k1a_stats(const float* __restrict__ x, float* __restrict__ stats) {
    int bc = blockIdx.x;                 // b*96 + c
    const float* xp = x + (size_t)bc * 4096;
    float s = 0.f, sq = 0.f;
    for (int i = threadIdx.x; i < 4096; i += 256) {
        float v = xp[i]; s += v; sq += v * v;
    }
    __shared__ float rs[256], rq[256];
    rs[threadIdx.x] = s; rq[threadIdx.x] = sq;
    __syncthreads();
    for (int off = 128; off > 0; off >>= 1) {
        if (threadIdx.x < off) {
            rs[threadIdx.x] += rs[threadIdx.x + off];
            rq[threadIdx.x] += rq[threadIdx.x + off];
        }
        __syncthreads();
    }
    if (threadIdx.x == 0) {
        float m = rs[0] * (1.f / 4096.f);
        float v = rq[0] * (1.f / 4096.f) - m * m;
        stats[bc] = m;
        stats[384 + bc] = rsqrtf(v + 1e-5f);
    }
}

// ------------------------------------------- k1b: normalize+SiLU, chunked write
__global__ void k1b_norm(const float* __restrict__ x, const float* __restrict__ stats,
                         const float* __restrict__ gamma, const float* __restrict__ beta,
                         float* __restrict__ h_store) {
    int chunk = blockIdx.x;
    int b = chunk >> 6, chh = (chunk >> 3) & 7, chw = chunk & 7;
    for (int i = threadIdx.x; i < 6144; i += 256) {
        int c = i % 96, pos = i / 96;
        int hh = chh * 8 + (pos >> 3), ww = chw * 8 + (pos & 7);
        int bc = b * 96 + c;
        float v = x[(((size_t)bc) * 64 + hh) * 64 + ww];
        float xn = (v - stats[bc]) * stats[384 + bc] * gamma[c] + beta[c];
        h_store[(size_t)chunk * 6144 + i] = siluf_(xn);   // [chunk][pos][c], coalesced
    }
}

// ------------------------------------------------- k2: LN(96) + in_proj 96->384
__global__ __launch_bounds__(512) void k2_ln_inproj(
        const float* __restrict__ h_store,
        const float* __restrict__ ln1_g, const float* __restrict__ ln1_b,
        const float* __restrict__ Win,          // (96, 384)
        float* __restrict__ xc_pre,             // [chunk][j<192][p]
        float* __restrict__ zbuf) {             // [chunk][j-192][p]
    int chunk = blockIdx.x;
    __shared__ float hs[64][97];
    const float* hp = h_store + (size_t)chunk * 6144;
    for (int i = threadIdx.x; i < 6144; i += 512) hs[i / 96][i % 96] = hp[i];
    __syncthreads();
    {   // LN: 8 lanes per position
        int p = threadIdx.x >> 3, o = threadIdx.x & 7;
        float s = 0.f, sq = 0.f;
        for (int j = 0; j < 12; j++) { float v = hs[p][o + 8 * j]; s += v; sq += v * v; }
        s += __shfl_xor(s, 1); sq += __shfl_xor(sq, 1);
        s += __shfl_xor(s, 2); sq += __shfl_xor(sq, 2);
        s += __shfl_xor(s, 4); sq += __shfl_xor(sq, 4);
        float m = s * (1.f / 96.f);
        float rinv = rsqrtf(sq * (1.f / 96.f) - m * m + 1e-5f);
        for (int j = 0; j < 12; j++) {
            int c = o + 8 * j;
            hs[p][c] = (hs[p][c] - m) * rinv * ln1_g[c] + ln1_b[c];
        }
    }
    __syncthreads();
    int p = threadIdx.x & 63;
    int jg = __builtin_amdgcn_readfirstlane(threadIdx.x >> 6);  // 0..7, wave-uniform
    int jbase = jg * 48;
    float acc[48];
    #pragma unroll
    for (int i = 0; i < 48; i++) acc[i] = 0.f;
    for (int c = 0; c < 96; c++) {
        float u = hs[p][c];
        const float* w = Win + c * 384 + jbase;   // wave-uniform -> scalar loads
        #pragma unroll
        for (int i = 0; i < 48; i++) acc[i] = fmaf(u, w[i], acc[i]);
    }
    if (jbase < 192) {
        float* o = xc_pre + (size_t)chunk * 12288 + jbase * 64 + p;
        #pragma unroll
        for (int i = 0; i < 48; i++) o[i * 64] = acc[i];
    } else {
        float* o = zbuf + (size_t)chunk * 12288 + (jbase - 192) * 64 + p;
        #pragma unroll
        for (int i = 0; i < 48; i++) o[i * 64] = acc[i];
    }
}

// --------------------------------- k3: depthwise 3x3 + bias + SiLU -> x0T[l][d]
__global__ __launch_bounds__(256) void k3_dwconv(
        const float* __restrict__ xc_pre, const float* __restrict__ conv_w,
        const float* __restrict__ conv_b, float* __restrict__ x0T) {
    int chunk = blockIdx.x;
    __shared__ float xcs[192][65];
    const float* in = xc_pre + (size_t)chunk * 12288;
    for (int i = threadIdx.x; i < 12288; i += 256) xcs[i >> 6][i & 63] = in[i];
    __syncthreads();
    for (int s = 0; s < 48; s++) {
        int o = threadIdx.x + s * 256;
        int d = o % 192, l = o / 192;
        int r = l >> 3, cc = l & 7;
        float acc = conv_b[d];
        #pragma unroll
        for (int dh = 0; dh < 3; dh++) {
            int rr = r + dh - 1;
            if (rr < 0 || rr > 7) continue;
            #pragma unroll
            for (int dw = 0; dw < 3; dw++) {
                int cw = cc + dw - 1;
                if (cw < 0 || cw > 7) continue;
                acc = fmaf(xcs[d][rr * 8 + cw], conv_w[d * 9 + dh * 3 + dw], acc);
            }
        }
        x0T[(size_t)chunk * 12288 + o] = siluf_(acc);   // o == l*192 + d, coalesced
    }
}

// -------------------- kproj: P[k][c][l] = sum_dd xpw[k][c][dd] * x0[dd][l]
// block = (chunk, k); natural-l order; k4 permutes on read.
__global__ __launch_bounds__(256) void kproj(
        const float* __restrict__ x0T, const float* __restrict__ xpw,
        float* __restrict__ Pg) {               // [(chunk*4+k)*38 + c][l]
    int blk = blockIdx.x;
    int chunk = blk >> 2, k = blk & 3;
    __shared__ float x0s[192][65];
    __shared__ float wls[40][192];
    const float* xg = x0T + (size_t)chunk * 12288;
    for (int i = threadIdx.x; i < 12288; i += 256) x0s[i % 192][i / 192] = xg[i];
    const float* wp = xpw + (size_t)k * 38 * 192;
    for (int i = threadIdx.x; i < 7296; i += 256) (&wls[0][0])[i] = wp[i];
    __syncthreads();
    int l = threadIdx.x & 63;
    int cg = __builtin_amdgcn_readfirstlane(threadIdx.x >> 6);  // 0..3
    int cbase = cg * 10;
    float acc[10];
    #pragma unroll
    for (int i = 0; i < 10; i++) acc[i] = 0.f;
    for (int dd = 0; dd < 192; dd++) {
        float u = x0s[dd][l];
        #pragma unroll
        for (int i = 0; i < 10; i++) acc[i] = fmaf(u, wls[cbase + i][dd], acc[i]);
    }
    float* og = Pg + (((size_t)(chunk * 4 + k)) * 38 + cbase) * 64 + l;
    #pragma unroll
    for (int i = 0; i < 10; i++)
        if (cbase + i < 38) og[(size_t)i * 64] = acc[i];
}

// ----------------- k4: 4 direction-groups scan concurrently, merge via LDS atomics
__global__ __launch_bounds__(768) void k4_scan(
        const float* __restrict__ x0T, const float* __restrict__ Pg,
        const float* __restrict__ dtw, const float* __restrict__ dtb,
        const float* __restrict__ A_logs, const float* __restrict__ Ds,
        float* __restrict__ y_g) {
    int chunk = blockIdx.x;
    __shared__ float x0s[192][65];
    __shared__ float yac[192][65];
    __shared__ float PL[4 * 38 * 64];
    const float* xg = x0T + (size_t)chunk * 12288;
    for (int i = threadIdx.x; i < 12288; i += 768) {
        int d = i % 192, l = i / 192;
        float v = xg[i];
        x0s[d][l] = v;
        float dsum = Ds[d] + Ds[192 + d] + Ds[384 + d] + Ds[576 + d];
        yac[d][l] = dsum * v;          // fold the D*u skip term into the init
    }
    const float* pg = Pg + (size_t)chunk * 9728;
    for (int i = threadIdx.x; i < 9728; i += 768) PL[i] = pg[i];
    __syncthreads();

    int k = threadIdx.x / 192;         // wave-uniform (192 = 3 waves)
    int d = threadIdx.x % 192;
    int gd = k * 192 + d;
    float w6[6];
    #pragma unroll
    for (int r = 0; r < 6; r++) w6[r] = dtw[gd * 6 + r];
    float bias = dtb[gd];
    float a[16];
    #pragma unroll
    for (int n = 0; n < 16; n++) a[n] = -__expf(A_logs[gd * 16 + n]);
    // powers fast path: valid when a[n] == (n+1)*a[0]  (true for this problem's A)
    bool pw = true;
    #pragma unroll
    for (int n = 1; n < 16; n++)
        pw = pw && (fabsf(a[n] - (float)(n + 1) * a[0]) <= 1e-4f * fabsf(a[n]) + 1e-6f);
    float hst[16];
    #pragma unroll
    for (int n = 0; n < 16; n++) hst[n] = 0.f;
    const float* PLk = PL + k * 38 * 64;

    if (pw) {
        float a0 = a[0];
        for (int l = 0; l < 64; l++) {
            int sl = sperm(k, l);
            float u = x0s[d][sl];
            float dp = bias;
            #pragma unroll
            for (int r = 0; r < 6; r++) dp = fmaf(PLk[r * 64 + sl], w6[r], dp);
            float ex = __expf(dp);
            float delta = (dp > 20.f) ? dp : __logf(1.f + ex);
            float du = delta * u;
            float e1 = __expf(delta * a0);
            float dA = e1;
            float y = 0.f;
            #pragma unroll
            for (int n = 0; n < 16; n++) {
                hst[n] = fmaf(hst[n], dA, du * PLk[(6 + n) * 64 + sl]);
                y = fmaf(hst[n], PLk[(22 + n) * 64 + sl], y);
                if (n < 15) dA *= e1;
            }
            atomicAdd(&yac[d][sl], y);
        }
    } else {
        for (int l = 0; l < 64; l++) {
            int sl = sperm(k, l);
            float u = x0s[d][sl];
            float dp = bias;
            #pragma unroll
            for (int r = 0; r < 6; r++) dp = fmaf(PLk[r * 64 + sl], w6[r], dp);
            float ex = __expf(dp);
            float delta = (dp > 20.f) ? dp : __logf(1.f + ex);
            float du = delta * u;
            float y = 0.f;
            #pragma unroll
            for (int n = 0; n < 16; n++) {
                float e = __expf(delta * a[n]);
                hst[n] = fmaf(hst[n], e, du * PLk[(6 + n) * 64 + sl]);
                y = fmaf(hst[n], PLk[(22 + n) * 64 + sl], y);
            }
            atomicAdd(&yac[d][sl], y);
        }
    }
    __syncthreads();
    float* yo = y_g + (size_t)chunk * 12288;
    for (int i = threadIdx.x; i < 12288; i += 768)
        yo[i] = yac[i % 192][i / 192];      // [l][d], coalesced
}

// ------------------- k5: LN(192)*silu(z) -> out_proj + residual + final blend
__global__ __launch_bounds__(256) void k5_out(
        const float* __restrict__ y_g, const float* __restrict__ zbuf,
        const float* __restrict__ og, const float* __restrict__ ob,
        const float* __restrict__ Wout,        // (192, 96)
        const float* __restrict__ h_store, const float* __restrict__ x,
        const float* __restrict__ alpha, float* __restrict__ out) {
    int chunk = blockIdx.x;
    __shared__ float ys[64][193];
    __shared__ float zs[64][193];
    const float* yp = y_g + (size_t)chunk * 12288;
    const float* zp = zbuf + (size_t)chunk * 12288;
    for (int i = threadIdx.x; i < 12288; i += 256) {
        ys[i / 192][i % 192] = yp[i];     // [p][i]
        zs[i % 64][i / 64] = zp[i];       // zbuf[j][p] -> zs[p][j]
    }
    __syncthreads();
    {   // LN over 192 + gate, 4 lanes per position
        int p = threadIdx.x >> 2, q = threadIdx.x & 3;
        float s = 0.f, sq = 0.f;
        for (int j = 0; j < 48; j++) { float v = ys[p][q + 4 * j]; s += v; sq += v * v; }
        s += __shfl_xor(s, 1); sq += __shfl_xor(sq, 1);
        s += __shfl_xor(s, 2); sq += __shfl_xor(sq, 2);
        float m = s * (1.f / 192.f);
        float rinv = rsqrtf(sq * (1.f / 192.f) - m * m + 1e-5f);
        for (int j = 0; j < 48; j++) {
            int i = q + 4 * j;
            float ln = (ys[p][i] - m) * rinv * og[i] + ob[i];
            ys[p][i] = ln * siluf_(zs[p][i]);
        }
    }
    __syncthreads();
    int p = threadIdx.x & 63;
    int cg = __builtin_amdgcn_readfirstlane(threadIdx.x >> 6);  // 0..3
    int cbase = cg * 24;
    float acc[24];
    #pragma unroll
    for (int i = 0; i < 24; i++) acc[i] = 0.f;
    for (int dd = 0; dd < 192; dd++) {
        float u = ys[p][dd];
        const float* w = Wout + dd * 96 + cbase;   // wave-uniform -> scalar loads
        #pragma unroll
        for (int i = 0; i < 24; i++) acc[i] = fmaf(u, w[i], acc[i]);
    }
    float al = alpha[0];
    int b = chunk >> 6, chh = (chunk >> 3) & 7, chw = chunk & 7;
    int hh = chh * 8 + (p >> 3), ww = chw * 8 + (p & 7);
    const float* hp = h_store + (size_t)chunk * 6144 + p * 96 + cbase;
    #pragma unroll
    for (int i = 0; i < 24; i++) {
        int c = cbase + i;
        float hnew = hp[i] + acc[i];
        size_t gi = (((size_t)(b * 96 + c)) * 64 + hh) * 64 + ww;
        out[gi] = x[gi] + al * hnew;
    }
}

extern "C" void kernel_launch(void* const* d_in, const int* in_sizes, int n_in,
                              void* d_out, int out_size, void* d_ws, size_t ws_size,
                              hipStream_t stream) {
    const float* x        = (const float*)d_in[0];
    const float* gamma    = (const float*)d_in[1];
    const float* beta     = (const float*)d_in[2];
    const float* alpha    = (const float*)d_in[3];
    const float* ln1_g    = (const float*)d_in[4];
    const float* ln1_b    = (const float*)d_in[5];
    const float* in_proj  = (const float*)d_in[6];
    const float* conv_w   = (const float*)d_in[7];
    const float* conv_b   = (const float*)d_in[8];
    const float* x_proj   = (const float*)d_in[9];
    const float* dt_w     = (const float*)d_in[10];
    const float* dt_b     = (const float*)d_in[11];
    const float* A_logs   = (const float*)d_in[12];
    const float* Ds       = (const float*)d_in[13];
    const float* onorm_g  = (const float*)d_in[14];
    const float* onorm_b  = (const float*)d_in[15];
    const float* out_proj = (const float*)d_in[16];
    float* out = (float*)d_out;

    float* ws      = (float*)d_ws;
    float* h_store = ws;                      // 1,572,864 f
    float* xc_pre  = ws + 1572864;            // 3,145,728 f (Pg reuses after k3)
    float* zbuf    = xc_pre + 3145728;        // 3,145,728 f
    float* x0T     = zbuf + 3145728;          // 3,145,728 f (y_g reuses after k4 staging)
    float* stats   = x0T + 3145728;           // 768 f
    float* Pg      = xc_pre;                  // alias: xc_pre dead after k3
    float* y_g     = x0T;                     // alias: in-place per chunk after LDS staging

    hipLaunchKernelGGL(k1a_stats, dim3(384), dim3(256), 0, stream, x, stats);
    hipLaunchKernelGGL(k1b_norm, dim3(256), dim3(256), 0, stream,
                       x, stats, gamma, beta, h_store);
    hipLaunchKernelGGL(k2_ln_inproj, dim3(256), dim3(512), 0, stream,
                       h_store, ln1_g, ln1_b, in_proj, xc_pre, zbuf);
    hipLaunchKernelGGL(k3_dwconv, dim3(256), dim3(256), 0, stream,
                       xc_pre, conv_w, conv_b, x0T);
    hipLaunchKernelGGL(kproj, dim3(1024), dim3(256), 0, stream,
                       x0T, x_proj, Pg);
    hipLaunchKernelGGL(k4_scan, dim3(256), dim3(768), 0, stream,
                       x0T, Pg, dt_w, dt_b, A_logs, Ds, y_g);
    hipLaunchKernelGGL(k5_out, dim3(256), dim3(256), 0, stream,
                       y_g, zbuf, onorm_g, onorm_b, out_proj, h_store, x, alpha, out);
}

// Round 3
// 259.760 us; speedup vs baseline: 2.7928x; 1.1589x over previous
//
#include <hip/hip_runtime.h>
#include <math.h>

// Problem constants
#define NCHUNK 256   // B * (H/CS) * (W/CS) = 4*8*8
#define CCH    96    // C
#define DNC    192   // 2*C
#define LC     64    // CS*CS
#define NST    16    // state dim N
#define DTR    6     // dt rank
#define PROW   48    // padded P row: [0..5]=dts, [8..23]=B, [24..39]=C

__device__ __forceinline__ float siluf_(float x) {
    return x / (1.f + __expf(-x));
}

// Direction permutation: xs[k][d][l] = x0[d][sperm(k,l)]; output of scan step l
// for direction k lands at spatial position sperm(k,l) (all involutions).
__device__ __forceinline__ int sperm(int k, int l) {
    int t = (k & 1) ? (((l & 7) << 3) | (l >> 3)) : l;
    return (k & 2) ? (63 - t) : t;
}

// ---------------------------------------------------------------- k1a: stats
__global__ void k1a_stats(const float* __restrict__ x, float* __restrict__ stats) {
    int bc = blockIdx.x;                 // b*96 + c
    const float* xp = x + (size_t)bc * 4096;
    float s = 0.f, sq = 0.f;
    for (int i = threadIdx.x; i < 4096; i += 256) {
        float v = xp[i]; s += v; sq += v * v;
    }
    __shared__ float rs[256], rq[256];
    rs[threadIdx.x] = s; rq[threadIdx.x] = sq;
    __syncthreads();
    for (int off = 128; off > 0; off >>= 1) {
        if (threadIdx.x < off) {
            rs[threadIdx.x] += rs[threadIdx.x + off];
            rq[threadIdx.x] += rq[threadIdx.x + off];
        }
        __syncthreads();
    }
    if (threadIdx.x == 0) {
        float m = rs[0] * (1.f / 4096.f);
        float v = rq[0] * (1.f / 4096.f) - m * m;
        stats[bc] = m;
        stats[384 + bc] = rsqrtf(v + 1e-5f);
    }
}

// ------------------------------------------- k1b: normalize+SiLU, chunked write
__global__ void k1b_norm(const float* __restrict__ x, const float* __restrict__ stats,
                         const float* __restrict__ gamma, const float* __restrict__ beta,
                         float* __restrict__ h_store) {
    int chunk = blockIdx.x;
    int b = chunk >> 6, chh = (chunk >> 3) & 7, chw = chunk & 7;
    for (int i = threadIdx.x; i < 6144; i += 256) {
        int c = i % 96, pos = i / 96;
        int hh = chh * 8 + (pos >> 3), ww = chw * 8 + (pos & 7);
        int bc = b * 96 + c;
        float v = x[(((size_t)bc) * 64 + hh) * 64 + ww];
        float xn = (v - stats[bc]) * stats[384 + bc] * gamma[c] + beta[c];
        h_store[(size_t)chunk * 6144 + i] = siluf_(xn);   // [chunk][pos][c]
    }
}

// ------------------------------------------------- k2: LN(96) + in_proj 96->384
__global__ __launch_bounds__(512) void k2_ln_inproj(
        const float* __restrict__ h_store,
        const float* __restrict__ ln1_g, const float* __restrict__ ln1_b,
        const float* __restrict__ Win,          // (96, 384)
        float* __restrict__ xc_pre,             // [chunk][j<192][p]
        float* __restrict__ zbuf) {             // [chunk][j-192][p]
    int chunk = blockIdx.x;
    __shared__ float hs[64][97];
    const float* hp = h_store + (size_t)chunk * 6144;
    for (int i = threadIdx.x; i < 6144; i += 512) hs[i / 96][i % 96] = hp[i];
    __syncthreads();
    {   // LN: 8 lanes per position
        int p = threadIdx.x >> 3, o = threadIdx.x & 7;
        float s = 0.f, sq = 0.f;
        for (int j = 0; j < 12; j++) { float v = hs[p][o + 8 * j]; s += v; sq += v * v; }
        s += __shfl_xor(s, 1); sq += __shfl_xor(sq, 1);
        s += __shfl_xor(s, 2); sq += __shfl_xor(sq, 2);
        s += __shfl_xor(s, 4); sq += __shfl_xor(sq, 4);
        float m = s * (1.f / 96.f);
        float rinv = rsqrtf(sq * (1.f / 96.f) - m * m + 1e-5f);
        for (int j = 0; j < 12; j++) {
            int c = o + 8 * j;
            hs[p][c] = (hs[p][c] - m) * rinv * ln1_g[c] + ln1_b[c];
        }
    }
    __syncthreads();
    int p = threadIdx.x & 63;
    int jg = __builtin_amdgcn_readfirstlane(threadIdx.x >> 6);  // 0..7, wave-uniform
    int jbase = jg * 48;
    float acc[48];
    #pragma unroll
    for (int i = 0; i < 48; i++) acc[i] = 0.f;
    for (int c = 0; c < 96; c++) {
        float u = hs[p][c];
        const float* w = Win + c * 384 + jbase;   // wave-uniform -> scalar loads
        #pragma unroll
        for (int i = 0; i < 48; i++) acc[i] = fmaf(u, w[i], acc[i]);
    }
    if (jbase < 192) {
        float* o = xc_pre + (size_t)chunk * 12288 + jbase * 64 + p;
        #pragma unroll
        for (int i = 0; i < 48; i++) o[i * 64] = acc[i];
    } else {
        float* o = zbuf + (size_t)chunk * 12288 + (jbase - 192) * 64 + p;
        #pragma unroll
        for (int i = 0; i < 48; i++) o[i * 64] = acc[i];
    }
}

// --------------------------------- k3: depthwise 3x3 + bias + SiLU -> x0N[d][l]
__global__ __launch_bounds__(256) void k3_dwconv(
        const float* __restrict__ xc_pre, const float* __restrict__ conv_w,
        const float* __restrict__ conv_b, float* __restrict__ x0N) {
    int chunk = blockIdx.x;
    __shared__ float xcs[192][65];
    const float* in = xc_pre + (size_t)chunk * 12288;
    for (int i = threadIdx.x; i < 12288; i += 256) xcs[i >> 6][i & 63] = in[i];
    __syncthreads();
    for (int s = 0; s < 48; s++) {
        int o = threadIdx.x + s * 256;
        int d = o >> 6, l = o & 63;
        int r = l >> 3, cc = l & 7;
        float acc = conv_b[d];
        #pragma unroll
        for (int dh = 0; dh < 3; dh++) {
            int rr = r + dh - 1;
            if (rr < 0 || rr > 7) continue;
            #pragma unroll
            for (int dw = 0; dw < 3; dw++) {
                int cw = cc + dw - 1;
                if (cw < 0 || cw > 7) continue;
                acc = fmaf(xcs[d][rr * 8 + cw], conv_w[d * 9 + dh * 3 + dw], acc);
            }
        }
        x0N[(size_t)chunk * 12288 + o] = siluf_(acc);   // o == d*64 + l, coalesced
    }
}

// -------------------- kproj: P rows [(chunk*4+k)*64 + l][48]
// slot map: c<6 -> c (dts), 6..21 -> c+2 (B at 8..23), 22..37 -> c+2 (C at 24..39)
__global__ __launch_bounds__(256) void kproj(
        const float* __restrict__ x0N, const float* __restrict__ xpw,
        float* __restrict__ Pg) {
    int blk = blockIdx.x;
    int chunk = blk >> 2, kk = blk & 3;
    __shared__ float wT[192][PROW];    // wT[dd][c], reused as pT[64][48] after
    const float* wp = xpw + (size_t)kk * 38 * 192;
    for (int i = threadIdx.x; i < 7296; i += 256) {
        int c = i / 192, dd = i % 192;
        wT[dd][c] = wp[i];
    }
    for (int i = threadIdx.x; i < 192 * 10; i += 256)
        wT[i / 10][38 + i % 10] = 0.f;
    __syncthreads();
    int l = threadIdx.x & 63;
    int cg = __builtin_amdgcn_readfirstlane(threadIdx.x >> 6);  // 0..3
    int cbase = cg * 12;
    float acc[12];
    #pragma unroll
    for (int i = 0; i < 12; i++) acc[i] = 0.f;
    const float* xrow = x0N + (size_t)chunk * 12288 + l;
    for (int dd = 0; dd < 192; dd++) {
        float u = xrow[(size_t)dd * 64];                 // coalesced global
        const float4* w4 = (const float4*)&wT[dd][cbase]; // broadcast b128 x3
        float4 wa = w4[0], wb = w4[1], wc = w4[2];
        acc[0] = fmaf(u, wa.x, acc[0]); acc[1] = fmaf(u, wa.y, acc[1]);
        acc[2] = fmaf(u, wa.z, acc[2]); acc[3] = fmaf(u, wa.w, acc[3]);
        acc[4] = fmaf(u, wb.x, acc[4]); acc[5] = fmaf(u, wb.y, acc[5]);
        acc[6] = fmaf(u, wb.z, acc[6]); acc[7] = fmaf(u, wb.w, acc[7]);
        acc[8] = fmaf(u, wc.x, acc[8]); acc[9] = fmaf(u, wc.y, acc[9]);
        acc[10] = fmaf(u, wc.z, acc[10]); acc[11] = fmaf(u, wc.w, acc[11]);
    }
    __syncthreads();               // done reading wT; reuse as pT
    float* pT = &wT[0][0];         // pT[l*48 + slot]
    for (int i = threadIdx.x; i < 3072; i += 256) pT[i] = 0.f;
    __syncthreads();
    #pragma unroll
    for (int i = 0; i < 12; i++) {
        int c = cbase + i;
        if (c < 38) {
            int slot = c + (c >= 6 ? 2 : 0);
            pT[l * PROW + slot] = acc[i];
        }
    }
    __syncthreads();
    float* og = Pg + (size_t)(chunk * 4 + kk) * 3072;
    for (int i = threadIdx.x; i < 3072; i += 256) og[i] = pT[i];  // coalesced
}

// ----------------- k4: 4 direction-groups scan concurrently, merge via LDS atomics
// B/C/dts come from Pg via wave-uniform scalar loads; LDS holds only x0 + yac.
__global__ __launch_bounds__(768) void k4_scan(
        const float* __restrict__ x0N, const float* __restrict__ Pg,
        const float* __restrict__ dtw, const float* __restrict__ dtb,
        const float* __restrict__ A_logs, const float* __restrict__ Ds,
        float* __restrict__ y_g) {
    int chunk = blockIdx.x;
    __shared__ float x0s[192][65];
    __shared__ float yac[192][65];
    const float* xg = x0N + (size_t)chunk * 12288;
    for (int i = threadIdx.x; i < 12288; i += 768) {
        int d = i >> 6, l = i & 63;
        float v = xg[i];
        x0s[d][l] = v;
        float dsum = Ds[d] + Ds[192 + d] + Ds[384 + d] + Ds[576 + d];
        yac[d][l] = dsum * v;          // fold the D*u skip term into the init
    }
    __syncthreads();

    int k = __builtin_amdgcn_readfirstlane(threadIdx.x / 192);  // wave-uniform
    int d = threadIdx.x - k * 192;
    int gd = k * 192 + d;
    float w6[6];
    #pragma unroll
    for (int r = 0; r < 6; r++) w6[r] = dtw[gd * 6 + r];
    float bias = dtb[gd];
    float a[16];
    #pragma unroll
    for (int n = 0; n < 16; n++) a[n] = -__expf(A_logs[gd * 16 + n]);
    bool pw = true;
    #pragma unroll
    for (int n = 1; n < 16; n++)
        pw = pw && (fabsf(a[n] - (float)(n + 1) * a[0]) <= 1e-4f * fabsf(a[n]) + 1e-6f);
    float hst[16];
    #pragma unroll
    for (int n = 0; n < 16; n++) hst[n] = 0.f;
    const float* pbase = Pg + (size_t)(chunk * 4 + k) * 3072;   // uniform

    if (__all(pw)) {
        float a0 = a[0];
        for (int l = 0; l < 64; l++) {
            int sl = sperm(k, l);
            const float* row = pbase + sl * PROW;   // uniform -> s_load
            float u = x0s[d][sl];
            float dp = bias;
            #pragma unroll
            for (int r = 0; r < 6; r++) dp = fmaf(row[r], w6[r], dp);
            float ex = __expf(dp);
            float delta = (dp > 20.f) ? dp : __logf(1.f + ex);
            float du = delta * u;
            // log-depth ladder of e1^(n+1)
            float e1 = __expf(delta * a0);
            float p[16];
            p[0] = e1;
            p[1] = e1 * e1;
            p[2] = p[1] * e1;   p[3] = p[1] * p[1];
            p[4] = p[3] * e1;   p[5] = p[3] * p[1];
            p[6] = p[3] * p[2]; p[7] = p[3] * p[3];
            p[8] = p[7] * e1;   p[9] = p[7] * p[1];
            p[10] = p[7] * p[2]; p[11] = p[7] * p[3];
            p[12] = p[7] * p[4]; p[13] = p[7] * p[5];
            p[14] = p[7] * p[6]; p[15] = p[7] * p[7];
            float y0 = 0.f, y1 = 0.f, y2 = 0.f, y3 = 0.f;
            #pragma unroll
            for (int n = 0; n < 16; n += 4) {
                hst[n]     = fmaf(hst[n],     p[n],     du * row[8 + n]);
                hst[n + 1] = fmaf(hst[n + 1], p[n + 1], du * row[9 + n]);
                hst[n + 2] = fmaf(hst[n + 2], p[n + 2], du * row[10 + n]);
                hst[n + 3] = fmaf(hst[n + 3], p[n + 3], du * row[11 + n]);
                y0 = fmaf(hst[n],     row[24 + n], y0);
                y1 = fmaf(hst[n + 1], row[25 + n], y1);
                y2 = fmaf(hst[n + 2], row[26 + n], y2);
                y3 = fmaf(hst[n + 3], row[27 + n], y3);
            }
            atomicAdd(&yac[d][sl], (y0 + y1) + (y2 + y3));
        }
    } else {
        for (int l = 0; l < 64; l++) {
            int sl = sperm(k, l);
            const float* row = pbase + sl * PROW;
            float u = x0s[d][sl];
            float dp = bias;
            #pragma unroll
            for (int r = 0; r < 6; r++) dp = fmaf(row[r], w6[r], dp);
            float ex = __expf(dp);
            float delta = (dp > 20.f) ? dp : __logf(1.f + ex);
            float du = delta * u;
            float y = 0.f;
            #pragma unroll
            for (int n = 0; n < 16; n++) {
                float e = __expf(delta * a[n]);
                hst[n] = fmaf(hst[n], e, du * row[8 + n]);
                y = fmaf(hst[n], row[24 + n], y);
            }
            atomicAdd(&yac[d][sl], y);
        }
    }
    __syncthreads();
    float* yo = y_g + (size_t)chunk * 12288;
    for (int i = threadIdx.x; i < 12288; i += 768)
        yo[i] = yac[i % 192][i / 192];      // [l][d], coalesced
}

// ------------------- k5: LN(192)*silu(z) -> out_proj + residual + final blend
__global__ __launch_bounds__(256) void k5_out(
        const float* __restrict__ y_g, const float* __restrict__ zbuf,
        const float* __restrict__ og, const float* __restrict__ ob,
        const float* __restrict__ Wout,        // (192, 96)
        const float* __restrict__ h_store, const float* __restrict__ x,
        const float* __restrict__ alpha, float* __restrict__ out) {
    int chunk = blockIdx.x;
    __shared__ float ys[64][193];
    __shared__ float zs[64][193];
    const float* yp = y_g + (size_t)chunk * 12288;
    const float* zp = zbuf + (size_t)chunk * 12288;
    for (int i = threadIdx.x; i < 12288; i += 256) {
        ys[i / 192][i % 192] = yp[i];     // [p][i]
        zs[i % 64][i / 64] = zp[i];       // zbuf[j][p] -> zs[p][j]
    }
    __syncthreads();
    {   // LN over 192 + gate, 4 lanes per position
        int p = threadIdx.x >> 2, q = threadIdx.x & 3;
        float s = 0.f, sq = 0.f;
        for (int j = 0; j < 48; j++) { float v = ys[p][q + 4 * j]; s += v; sq += v * v; }
        s += __shfl_xor(s, 1); sq += __shfl_xor(sq, 1);
        s += __shfl_xor(s, 2); sq += __shfl_xor(sq, 2);
        float m = s * (1.f / 192.f);
        float rinv = rsqrtf(sq * (1.f / 192.f) - m * m + 1e-5f);
        for (int j = 0; j < 48; j++) {
            int i = q + 4 * j;
            float ln = (ys[p][i] - m) * rinv * og[i] + ob[i];
            ys[p][i] = ln * siluf_(zs[p][i]);
        }
    }
    __syncthreads();
    int p = threadIdx.x & 63;
    int cg = __builtin_amdgcn_readfirstlane(threadIdx.x >> 6);  // 0..3
    int cbase = cg * 24;
    float acc[24];
    #pragma unroll
    for (int i = 0; i < 24; i++) acc[i] = 0.f;
    for (int dd = 0; dd < 192; dd++) {
        float u = ys[p][dd];
        const float* w = Wout + dd * 96 + cbase;   // wave-uniform -> scalar loads
        #pragma unroll
        for (int i = 0; i < 24; i++) acc[i] = fmaf(u, w[i], acc[i]);
    }
    float al = alpha[0];
    int b = chunk >> 6, chh = (chunk >> 3) & 7, chw = chunk & 7;
    int hh = chh * 8 + (p >> 3), ww = chw * 8 + (p & 7);
    const float* hp = h_store + (size_t)chunk * 6144 + p * 96 + cbase;
    #pragma unroll
    for (int i = 0; i < 24; i++) {
        int c = cbase + i;
        float hnew = hp[i] + acc[i];
        size_t gi = (((size_t)(b * 96 + c)) * 64 + hh) * 64 + ww;
        out[gi] = x[gi] + al * hnew;
    }
}

extern "C" void kernel_launch(void* const* d_in, const int* in_sizes, int n_in,
                              void* d_out, int out_size, void* d_ws, size_t ws_size,
                              hipStream_t stream) {
    const float* x        = (const float*)d_in[0];
    const float* gamma    = (const float*)d_in[1];
    const float* beta     = (const float*)d_in[2];
    const float* alpha    = (const float*)d_in[3];
    const float* ln1_g    = (const float*)d_in[4];
    const float* ln1_b    = (const float*)d_in[5];
    const float* in_proj  = (const float*)d_in[6];
    const float* conv_w   = (const float*)d_in[7];
    const float* conv_b   = (const float*)d_in[8];
    const float* x_proj   = (const float*)d_in[9];
    const float* dt_w     = (const float*)d_in[10];
    const float* dt_b     = (const float*)d_in[11];
    const float* A_logs   = (const float*)d_in[12];
    const float* Ds       = (const float*)d_in[13];
    const float* onorm_g  = (const float*)d_in[14];
    const float* onorm_b  = (const float*)d_in[15];
    const float* out_proj = (const float*)d_in[16];
    float* out = (float*)d_out;

    float* ws      = (float*)d_ws;
    float* h_store = ws;                      // 1,572,864 f
    float* xc_pre  = ws + 1572864;            // 3,145,728 f (Pg reuses after k3)
    float* zbuf    = xc_pre + 3145728;        // 3,145,728 f
    float* x0N     = zbuf + 3145728;          // 3,145,728 f (y_g reuses after k4 staging)
    float* stats   = x0N + 3145728;           // 768 f
    float* Pg      = xc_pre;                  // alias: xc_pre dead after k3
    float* y_g     = x0N;                     // alias: rewritten after k4 staging

    hipLaunchKernelGGL(k1a_stats, dim3(384), dim3(256), 0, stream, x, stats);
    hipLaunchKernelGGL(k1b_norm, dim3(256), dim3(256), 0, stream,
                       x, stats, gamma, beta, h_store);
    hipLaunchKernelGGL(k2_ln_inproj, dim3(256), dim3(512), 0, stream,
                       h_store, ln1_g, ln1_b, in_proj, xc_pre, zbuf);
    hipLaunchKernelGGL(k3_dwconv, dim3(256), dim3(256), 0, stream,
                       xc_pre, conv_w, conv_b, x0N);
    hipLaunchKernelGGL(kproj, dim3(1024), dim3(256), 0, stream,
                       x0N, x_proj, Pg);
    hipLaunchKernelGGL(k4_scan, dim3(256), dim3(768), 0, stream,
                       x0N, Pg, dt_w, dt_b, A_logs, Ds, y_g);
    hipLaunchKernelGGL(k5_out, dim3(256), dim3(256), 0, stream,
                       y_g, zbuf, onorm_g, onorm_b, out_proj, h_store, x, alpha, out);
}

// Round 4
// 217.917 us; speedup vs baseline: 3.3291x; 1.1920x over previous
//
#include <hip/hip_runtime.h>
#include <math.h>

// Problem constants
#define NCHUNK 256   // B * (H/CS) * (W/CS) = 4*8*8
#define CCH    96
#define DNC    192
#define NST    16
#define DTR    6
#define PROW   48    // padded P row: [0..5]=dts, [8..23]=B, [24..39]=C, rest 0

__device__ __forceinline__ float siluf_(float x) {
    return x / (1.f + __expf(-x));
}

// Direction permutation (involution): xs[k][d][l] = x0[d][sperm(k,l)]
__device__ __forceinline__ int sperm(int k, int l) {
    int t = (k & 1) ? (((l & 7) << 3) | (l >> 3)) : l;
    return (k & 2) ? (63 - t) : t;
}

// ---------------------------------------------------------------- k1a: stats
__global__ void k1a_stats(const float* __restrict__ x, float* __restrict__ stats) {
    int bc = blockIdx.x;                 // b*96 + c
    const float* xp = x + (size_t)bc * 4096;
    float s = 0.f, sq = 0.f;
    for (int i = threadIdx.x; i < 4096; i += 256) {
        float v = xp[i]; s += v; sq += v * v;
    }
    __shared__ float rs[256], rq[256];
    rs[threadIdx.x] = s; rq[threadIdx.x] = sq;
    __syncthreads();
    for (int off = 128; off > 0; off >>= 1) {
        if (threadIdx.x < off) {
            rs[threadIdx.x] += rs[threadIdx.x + off];
            rq[threadIdx.x] += rq[threadIdx.x + off];
        }
        __syncthreads();
    }
    if (threadIdx.x == 0) {
        float m = rs[0] * (1.f / 4096.f);
        float v = rq[0] * (1.f / 4096.f) - m * m;
        stats[bc] = m;
        stats[384 + bc] = rsqrtf(v + 1e-5f);
    }
}

// --------------- ksetup: transpose x_proj_w into padded slot layout
// wTg[k][dd][slot]: slot<6 -> dts c=slot; 8<=slot<40 -> c=slot-2 (B then C); else 0
__global__ void ksetup(const float* __restrict__ xpw, float* __restrict__ wTg) {
    int k = blockIdx.x;
    for (int i = threadIdx.x; i < 192 * PROW; i += 256) {
        int dd = i / PROW, slot = i % PROW;
        int c = -1;
        if (slot < 6) c = slot;
        else if (slot >= 8 && slot < 40) c = slot - 2;
        float v = (c >= 0) ? xpw[((size_t)k * 38 + c) * 192 + dd] : 0.f;
        wTg[((size_t)k * 192 + dd) * PROW + slot] = v;
    }
}

// ------------------------------- kfused: the whole per-chunk pipeline
__global__ __launch_bounds__(768, 1) void kfused(
        const float* __restrict__ x, const float* __restrict__ stats,
        const float* __restrict__ gamma, const float* __restrict__ beta,
        const float* __restrict__ ln1_g, const float* __restrict__ ln1_b,
        const float* __restrict__ Win,       // (96,384)
        const float* __restrict__ conv_w, const float* __restrict__ conv_b,
        const float* __restrict__ wTg,       // (4,192,48) slot layout
        const float* __restrict__ dtw, const float* __restrict__ dtb,
        const float* __restrict__ A_logs, const float* __restrict__ Ds,
        const float* __restrict__ og, const float* __restrict__ ob,
        const float* __restrict__ Wout,      // (192,96)
        const float* __restrict__ alpha,
        float* __restrict__ zg_all,          // [chunk][192][64]
        float* __restrict__ Pg_all,          // [chunk*4+k][64][48]
        float* __restrict__ out) {
    __shared__ float hs[64][97];    // silu(norm(x)) — lives to the end (residual)
    __shared__ float xln[64][97];   // LN1 output
    __shared__ float xc[192][65];   // conv input; REUSED as yac after conv
    __shared__ float x0[192][65];   // conv output; REUSED as g[64][193] after scan

    int chunk = blockIdx.x;
    int t = threadIdx.x;
    int b = chunk >> 6, chh = (chunk >> 3) & 7, chw = chunk & 7;

    // ---- ph1: load x-chunk, spatial norm + SiLU -> hs[pos][c]
    for (int i = t; i < 6144; i += 768) {
        int c = i >> 6, pos = i & 63;            // pos fastest: 8-float bursts
        int bc = b * 96 + c;
        int hh = chh * 8 + (pos >> 3), ww = chw * 8 + (pos & 7);
        float v = x[(((size_t)bc) * 64 + hh) * 64 + ww];
        float xn = (v - stats[bc]) * stats[384 + bc] * gamma[c] + beta[c];
        hs[pos][c] = siluf_(xn);
    }
    __syncthreads();

    // ---- ph2: LN over 96 per position -> xln
    if (t < 512) {
        int p = t >> 3, o = t & 7;
        float s = 0.f, sq = 0.f;
        for (int j = 0; j < 12; j++) { float v = hs[p][o + 8 * j]; s += v; sq += v * v; }
        s += __shfl_xor(s, 1); sq += __shfl_xor(sq, 1);
        s += __shfl_xor(s, 2); sq += __shfl_xor(sq, 2);
        s += __shfl_xor(s, 4); sq += __shfl_xor(sq, 4);
        float m = s * (1.f / 96.f);
        float rinv = rsqrtf(sq * (1.f / 96.f) - m * m + 1e-5f);
        for (int j = 0; j < 12; j++) {
            int c = o + 8 * j;
            xln[p][c] = (hs[p][c] - m) * rinv * ln1_g[c] + ln1_b[c];
        }
    }
    __syncthreads();

    // ---- ph3: in_proj GEMV 96->384; 12 waves x 32 cols (wave-uniform weights)
    {
        int p = t & 63;
        int wv = __builtin_amdgcn_readfirstlane(t >> 6);   // 0..11
        int jbase = wv * 32;
        float acc[32];
        #pragma unroll
        for (int i = 0; i < 32; i++) acc[i] = 0.f;
        for (int c = 0; c < 96; c++) {
            float u = xln[p][c];
            const float* w = Win + c * 384 + jbase;        // scalar loads
            #pragma unroll
            for (int i = 0; i < 32; i++) acc[i] = fmaf(u, w[i], acc[i]);
        }
        if (jbase < 192) {          // conv-input half -> LDS xc[d][p]
            #pragma unroll
            for (int i = 0; i < 32; i++) xc[jbase + i][p] = acc[i];
        } else {                    // z half -> global [j][p] (coalesced)
            float* zg = zg_all + (size_t)chunk * 12288 + (jbase - 192) * 64 + p;
            #pragma unroll
            for (int i = 0; i < 32; i++) zg[i * 64] = acc[i];
        }
    }
    __syncthreads();

    // ---- ph4: depthwise 3x3 conv + bias + SiLU -> x0[d][l]
    for (int s = 0; s < 16; s++) {
        int o = t + s * 768;
        int d = o >> 6, l = o & 63;
        int r = l >> 3, cc = l & 7;
        float acc = conv_b[d];
        #pragma unroll
        for (int dh = 0; dh < 3; dh++) {
            int rr = r + dh - 1;
            if (rr < 0 || rr > 7) continue;
            #pragma unroll
            for (int dw = 0; dw < 3; dw++) {
                int cw = cc + dw - 1;
                if (cw < 0 || cw > 7) continue;
                acc = fmaf(xc[d][rr * 8 + cw], conv_w[d * 9 + dh * 3 + dw], acc);
            }
        }
        x0[d][l] = siluf_(acc);
    }
    __syncthreads();

    // ---- ph5: P-projection -> Pg (slot layout), and yac init (reuse xc)
    {
        int k = __builtin_amdgcn_readfirstlane(t / 192);
        int tk = t - k * 192;
        int l = tk & 63;
        int cg = __builtin_amdgcn_readfirstlane(tk >> 6);  // 0..2
        int cbase = cg * 16;
        float acc[16];
        #pragma unroll
        for (int i = 0; i < 16; i++) acc[i] = 0.f;
        for (int dd = 0; dd < 192; dd++) {
            float u = x0[dd][l];
            const float* w = wTg + ((size_t)k * 192 + dd) * PROW + cbase;  // scalar
            #pragma unroll
            for (int i = 0; i < 16; i++) acc[i] = fmaf(u, w[i], acc[i]);
        }
        float* pg = Pg_all + (size_t)(chunk * 4 + k) * 3072 + l * PROW + cbase;
        #pragma unroll
        for (int i = 0; i < 16; i += 4)
            *(float4*)(pg + i) = make_float4(acc[i], acc[i+1], acc[i+2], acc[i+3]);
    }
    // yac init with folded D-term (xc is free now)
    for (int i = t; i < 12288; i += 768) {
        int d = i >> 6, l = i & 63;
        float dsum = Ds[d] + Ds[192 + d] + Ds[384 + d] + Ds[576 + d];
        xc[d][l] = dsum * x0[d][l];
    }
    __syncthreads();   // drains Pg stores (vmcnt 0 before barrier) -> s_loads see them

    // ---- ph6: selective scan, 4 direction-groups concurrent, merge into yac(=xc)
    {
        int k = __builtin_amdgcn_readfirstlane(t / 192);
        int d = t - k * 192;
        int gd = k * 192 + d;
        float w6[6];
        #pragma unroll
        for (int r = 0; r < 6; r++) w6[r] = dtw[gd * 6 + r];
        float bias = dtb[gd];
        float a[16];
        #pragma unroll
        for (int n = 0; n < 16; n++) a[n] = -__expf(A_logs[gd * 16 + n]);
        bool pw = true;
        #pragma unroll
        for (int n = 1; n < 16; n++)
            pw = pw && (fabsf(a[n] - (float)(n + 1) * a[0]) <= 1e-4f * fabsf(a[n]) + 1e-6f);
        float hst[16];
        #pragma unroll
        for (int n = 0; n < 16; n++) hst[n] = 0.f;
        const float* pbase = Pg_all + (size_t)(chunk * 4 + k) * 3072;  // uniform

        if (__all(pw)) {
            float a0 = a[0];
            for (int l = 0; l < 64; l++) {
                int sl = sperm(k, l);
                const float* row = pbase + sl * PROW;   // uniform -> s_load
                float u = x0[d][sl];
                float dp = bias;
                #pragma unroll
                for (int r = 0; r < 6; r++) dp = fmaf(row[r], w6[r], dp);
                float ex = __expf(dp);
                float delta = (dp > 20.f) ? dp : __logf(1.f + ex);
                float du = delta * u;
                float e1 = __expf(delta * a0);
                float p[16];
                p[0] = e1;
                p[1] = e1 * e1;
                p[2] = p[1] * e1;   p[3] = p[1] * p[1];
                p[4] = p[3] * e1;   p[5] = p[3] * p[1];
                p[6] = p[3] * p[2]; p[7] = p[3] * p[3];
                p[8] = p[7] * e1;   p[9] = p[7] * p[1];
                p[10] = p[7] * p[2]; p[11] = p[7] * p[3];
                p[12] = p[7] * p[4]; p[13] = p[7] * p[5];
                p[14] = p[7] * p[6]; p[15] = p[7] * p[7];
                float y0 = 0.f, y1 = 0.f, y2 = 0.f, y3 = 0.f;
                #pragma unroll
                for (int n = 0; n < 16; n += 4) {
                    hst[n]     = fmaf(hst[n],     p[n],     du * row[8 + n]);
                    hst[n + 1] = fmaf(hst[n + 1], p[n + 1], du * row[9 + n]);
                    hst[n + 2] = fmaf(hst[n + 2], p[n + 2], du * row[10 + n]);
                    hst[n + 3] = fmaf(hst[n + 3], p[n + 3], du * row[11 + n]);
                    y0 = fmaf(hst[n],     row[24 + n], y0);
                    y1 = fmaf(hst[n + 1], row[25 + n], y1);
                    y2 = fmaf(hst[n + 2], row[26 + n], y2);
                    y3 = fmaf(hst[n + 3], row[27 + n], y3);
                }
                atomicAdd(&xc[d][sl], (y0 + y1) + (y2 + y3));
            }
        } else {
            for (int l = 0; l < 64; l++) {
                int sl = sperm(k, l);
                const float* row = pbase + sl * PROW;
                float u = x0[d][sl];
                float dp = bias;
                #pragma unroll
                for (int r = 0; r < 6; r++) dp = fmaf(row[r], w6[r], dp);
                float ex = __expf(dp);
                float delta = (dp > 20.f) ? dp : __logf(1.f + ex);
                float du = delta * u;
                float y = 0.f;
                #pragma unroll
                for (int n = 0; n < 16; n++) {
                    float e = __expf(delta * a[n]);
                    hst[n] = fmaf(hst[n], e, du * row[8 + n]);
                    y = fmaf(hst[n], row[24 + n], y);
                }
                atomicAdd(&xc[d][sl], y);
            }
        }
    }
    __syncthreads();

    // ---- ph7: outnorm LN(192) per position + silu(z) gate -> g (reuse x0 space)
    float* gbuf = &x0[0][0];        // g[p][i] at p*193 + i
    if (t < 512) {
        int p = t >> 3, o = t & 7;
        float s = 0.f, sq = 0.f;
        for (int j = 0; j < 24; j++) { float v = xc[o + 8 * j][p]; s += v; sq += v * v; }
        s += __shfl_xor(s, 1); sq += __shfl_xor(sq, 1);
        s += __shfl_xor(s, 2); sq += __shfl_xor(sq, 2);
        s += __shfl_xor(s, 4); sq += __shfl_xor(sq, 4);
        float m = s * (1.f / 192.f);
        float rinv = rsqrtf(sq * (1.f / 192.f) - m * m + 1e-5f);
        const float* zg = zg_all + (size_t)chunk * 12288;
        for (int j = 0; j < 24; j++) {
            int i = o + 8 * j;
            float ln = (xc[i][p] - m) * rinv * og[i] + ob[i];
            float zv = zg[i * 64 + p];              // line-coalesced per wave
            gbuf[p * 193 + i] = ln * siluf_(zv);
        }
    }
    __syncthreads();

    // ---- ph8: out_proj GEMV 192->96 + h residual + final blend, 12 waves x 8 c
    {
        int p = t & 63;
        int wv = __builtin_amdgcn_readfirstlane(t >> 6);   // 0..11
        int cbase = wv * 8;
        float acc[8];
        #pragma unroll
        for (int i = 0; i < 8; i++) acc[i] = 0.f;
        for (int dd = 0; dd < 192; dd++) {
            float u = gbuf[p * 193 + dd];
            const float* w = Wout + dd * 96 + cbase;       // scalar loads
            #pragma unroll
            for (int i = 0; i < 8; i++) acc[i] = fmaf(u, w[i], acc[i]);
        }
        float al = alpha[0];
        int hh = chh * 8 + (p >> 3), ww = chw * 8 + (p & 7);
        #pragma unroll
        for (int i = 0; i < 8; i++) {
            int c = cbase + i;
            float hnew = hs[p][c] + acc[i];
            size_t gi = (((size_t)(b * 96 + c)) * 64 + hh) * 64 + ww;
            out[gi] = x[gi] + al * hnew;
        }
    }
}

extern "C" void kernel_launch(void* const* d_in, const int* in_sizes, int n_in,
                              void* d_out, int out_size, void* d_ws, size_t ws_size,
                              hipStream_t stream) {
    const float* x        = (const float*)d_in[0];
    const float* gamma    = (const float*)d_in[1];
    const float* beta     = (const float*)d_in[2];
    const float* alpha    = (const float*)d_in[3];
    const float* ln1_g    = (const float*)d_in[4];
    const float* ln1_b    = (const float*)d_in[5];
    const float* in_proj  = (const float*)d_in[6];
    const float* conv_w   = (const float*)d_in[7];
    const float* conv_b   = (const float*)d_in[8];
    const float* x_proj   = (const float*)d_in[9];
    const float* dt_w     = (const float*)d_in[10];
    const float* dt_b     = (const float*)d_in[11];
    const float* A_logs   = (const float*)d_in[12];
    const float* Ds       = (const float*)d_in[13];
    const float* onorm_g  = (const float*)d_in[14];
    const float* onorm_b  = (const float*)d_in[15];
    const float* out_proj = (const float*)d_in[16];
    float* out = (float*)d_out;

    float* ws   = (float*)d_ws;
    float* stats = ws;                    // 768 f
    float* wTg   = ws + 768;              // 4*192*48 = 36,864 f
    float* zbuf  = wTg + 36864;           // 256*192*64 = 3,145,728 f
    float* Pg    = zbuf + 3145728;        // 256*4*64*48 = 786,432 f

    hipLaunchKernelGGL(k1a_stats, dim3(384), dim3(256), 0, stream, x, stats);
    hipLaunchKernelGGL(ksetup, dim3(4), dim3(256), 0, stream, x_proj, wTg);
    hipLaunchKernelGGL(kfused, dim3(256), dim3(768), 0, stream,
                       x, stats, gamma, beta, ln1_g, ln1_b, in_proj,
                       conv_w, conv_b, wTg, dt_w, dt_b, A_logs, Ds,
                       onorm_g, onorm_b, out_proj, alpha, zbuf, Pg, out);
}